// Round 1
// baseline (124.309 us; speedup 1.0000x reference)
//
#include <hip/hip_runtime.h>

#define NW   10
#define QDIM 1024   // 1 << NW

// One block per state vector. 512 threads; thread t owns amplitudes {t, t+512}
// for load/permute/reduce phases, and butterfly pair p=t for each gate.
__global__ __launch_bounds__(512) void qsa_kernel(
    const float* __restrict__ x,     // (nstates, 1024)
    const float* __restrict__ rx0,   // (10,)
    const float* __restrict__ ry0,   // (10,)
    const float* __restrict__ ry1,   // (10,)
    float* __restrict__ out)         // (nstates, 10)
{
    __shared__ float re[QDIM];
    __shared__ float im[QDIM];
    __shared__ float gA[NW][4];      // fused layer-1 gate: ar, ai, br, bi
    __shared__ float gB[NW][2];      // layer-2 RY: c, s
    __shared__ float red[8 * NW];    // cross-wave reduction scratch
    __shared__ float s_scale;

    const int t = threadIdx.x;       // 0..511
    const int n = blockIdx.x;
    const float* xr = x + (size_t)n * QDIM;

    // ---- load row, partial sum of squares ----
    const float v0 = xr[t];
    const float v1 = xr[t + 512];
    re[t]       = v0;
    re[t + 512] = v1;

    float ss = v0 * v0 + v1 * v1;
    #pragma unroll
    for (int off = 32; off > 0; off >>= 1)
        ss += __shfl_down(ss, off, 64);
    if ((t & 63) == 0) red[t >> 6] = ss;

    // ---- gate coefficients (threads 0..9) ----
    if (t < NW) {
        float cx, sx, cy0, sy0, cy1, sy1;
        sincosf(0.5f * rx0[t], &sx,  &cx);
        sincosf(0.5f * ry0[t], &sy0, &cy0);
        sincosf(0.5f * ry1[t], &sy1, &cy1);
        // G = RY(ry0) * RX(rx0) = [[a, b], [-conj(b), conj(a)]]
        gA[t][0] = cy0 * cx;    // ar
        gA[t][1] = sy0 * sx;    // ai
        gA[t][2] = -sy0 * cx;   // br
        gA[t][3] = -cy0 * sx;   // bi
        gB[t][0] = cy1;
        gB[t][1] = sy1;
    }
    __syncthreads();

    if (t == 0) {
        float s = 0.f;
        #pragma unroll
        for (int w = 0; w < 8; ++w) s += red[w];
        s_scale = 1.0f / fmaxf(sqrtf(s), 1e-12f);
    }
    __syncthreads();

    // ---- layer 1: fused RY*RX per wire (wire q -> bit shift 9-q) ----
    {
        // wire 0: stride 512, pair is exactly (t, t+512); im==0, fold in scale
        const float scale = s_scale;
        const float ar = gA[0][0], ai = gA[0][1], br = gA[0][2], bi = gA[0][3];
        const float r0 = re[t] * scale;
        const float r1 = re[t + 512] * scale;
        re[t]       =  ar * r0 + br * r1;
        im[t]       =  ai * r0 + bi * r1;
        re[t + 512] = -br * r0 + ar * r1;
        im[t + 512] =  bi * r0 - ai * r1;
        __syncthreads();
    }
    for (int q = 1; q < NW; ++q) {
        const int sh = 9 - q;
        const int m  = 1 << sh;
        const int i0 = ((t >> sh) << (sh + 1)) | (t & (m - 1));
        const int i1 = i0 | m;
        const float ar = gA[q][0], ai = gA[q][1], br = gA[q][2], bi = gA[q][3];
        const float r0 = re[i0], m0 = im[i0];
        const float r1 = re[i1], m1 = im[i1];
        re[i0] =  ar * r0 - ai * m0 + br * r1 - bi * m1;
        im[i0] =  ar * m0 + ai * r0 + br * m1 + bi * r1;
        re[i1] = -br * r0 - bi * m0 + ar * r1 + ai * m1;
        im[i1] = -br * m0 + bi * r0 + ar * m1 - ai * r1;
        __syncthreads();
    }

    // ---- CNOT ring fused into one gather ----
    // CNOT(k, (k+1)%10): new[i] = old[i ^ (bit(i, 9-k) << (9-((k+1)%10)))]
    // Compose gathers: apply k=9 first, then 8, ..., 0.
    {
        int ga = t, gb = t + 512;
        #pragma unroll
        for (int k = 9; k >= 0; --k) {
            const int cs = 9 - k;
            const int ts = 9 - ((k + 1) % NW);
            ga ^= ((ga >> cs) & 1) << ts;
            gb ^= ((gb >> cs) & 1) << ts;
        }
        const float pr0 = re[ga], pm0 = im[ga];
        const float pr1 = re[gb], pm1 = im[gb];
        __syncthreads();
        re[t]       = pr0; im[t]       = pm0;
        re[t + 512] = pr1; im[t + 512] = pm1;
        __syncthreads();
    }

    // ---- layer 2: RY per wire ----
    for (int q = 0; q < NW; ++q) {
        const int sh = 9 - q;
        const int m  = 1 << sh;
        const int i0 = ((t >> sh) << (sh + 1)) | (t & (m - 1));
        const int i1 = i0 | m;
        const float c = gB[q][0], s = gB[q][1];
        const float r0 = re[i0], m0 = im[i0];
        const float r1 = re[i1], m1 = im[i1];
        re[i0] = c * r0 - s * r1;  im[i0] = c * m0 - s * m1;
        re[i1] = s * r0 + c * r1;  im[i1] = s * m0 + c * m1;
        __syncthreads();
    }

    // ---- Z expectations: out[n][j] = sum_i |psi_i|^2 * (-1)^bit_j(i) ----
    float acc[NW];
    #pragma unroll
    for (int j = 0; j < NW; ++j) acc[j] = 0.f;
    #pragma unroll
    for (int k = 0; k < 2; ++k) {
        const int i = t + k * 512;
        const float p = re[i] * re[i] + im[i] * im[i];
        #pragma unroll
        for (int j = 0; j < NW; ++j)
            acc[j] += ((i >> (9 - j)) & 1) ? -p : p;
    }
    #pragma unroll
    for (int j = 0; j < NW; ++j) {
        #pragma unroll
        for (int off = 32; off > 0; off >>= 1)
            acc[j] += __shfl_down(acc[j], off, 64);
    }
    if ((t & 63) == 0) {
        const int w = t >> 6;
        #pragma unroll
        for (int j = 0; j < NW; ++j) red[w * NW + j] = acc[j];
    }
    __syncthreads();
    if (t < NW) {
        float s = 0.f;
        #pragma unroll
        for (int w = 0; w < 8; ++w) s += red[w * NW + t];
        out[(size_t)n * NW + t] = s;
    }
}

extern "C" void kernel_launch(void* const* d_in, const int* in_sizes, int n_in,
                              void* d_out, int out_size, void* d_ws, size_t ws_size,
                              hipStream_t stream) {
    const float* x   = (const float*)d_in[0];
    const float* rx0 = (const float*)d_in[1];
    const float* ry0 = (const float*)d_in[2];
    const float* ry1 = (const float*)d_in[3];
    float* out = (float*)d_out;
    const int nstates = in_sizes[0] / QDIM;   // 4096
    qsa_kernel<<<nstates, 512, 0, stream>>>(x, rx0, ry0, ry1, out);
}

// Round 2
// 85.870 us; speedup vs baseline: 1.4476x; 1.4476x over previous
//
#include <hip/hip_runtime.h>

#define NW   10
#define QDIM 1024

// ---------------------------------------------------------------------------
// CNOT-ring fused permutation: psi_final[i] = psi_in[gperm(i)].
// Bit-linear over GF(2): gperm(a ^ b) = gperm(a) ^ gperm(b).
__device__ __host__ __forceinline__ int gperm(int v) {
    #pragma unroll
    for (int k = 9; k >= 0; --k) {
        const int cs = 9 - k;                 // control bit (qubit k)
        const int ts = 9 - ((k + 1) % NW);    // target bit (qubit k+1 mod 10)
        v ^= ((v >> cs) & 1) << ts;
    }
    return v;
}

// Padded physical index for the LDS float2 state array.
// Keeps 16B alignment (pads even) and removes all bank conflicts:
// every trip's pattern hits the pure-bandwidth floor.
__device__ __forceinline__ int P2i(int i) {
    return i + ((i >> 4) << 1) + ((i >> 8) << 1);
}

// ---------------------------------------------------------------------------
// Register butterflies on the 4 locally-owned bits (amps re[16]/im[16]).
// Complex gate [[a,b],[-conj(b),conj(a)]]:
template<int SH>
__device__ __forceinline__ void cgates(float* re, float* im,
                                       float ar, float ai, float br, float bi) {
    #pragma unroll
    for (int base = 0; base < 16; base += (2 << SH)) {
        #pragma unroll
        for (int off = 0; off < (1 << SH); ++off) {
            const int r0 = base + off, r1 = r0 + (1 << SH);
            const float v0r = re[r0], v0i = im[r0];
            const float v1r = re[r1], v1i = im[r1];
            re[r0] =  ar * v0r - ai * v0i + br * v1r - bi * v1i;
            im[r0] =  ar * v0i + ai * v0r + br * v1i + bi * v1r;
            re[r1] = -br * v0r - bi * v0i + ar * v1r + ai * v1i;
            im[r1] =  bi * v0r - br * v0i + ar * v1i - ai * v1r;
        }
    }
}

// Real RY gate [[c,-s],[s,c]] applied to complex amps:
template<int SH>
__device__ __forceinline__ void rgates(float* re, float* im, float c, float s) {
    #pragma unroll
    for (int base = 0; base < 16; base += (2 << SH)) {
        #pragma unroll
        for (int off = 0; off < (1 << SH); ++off) {
            const int r0 = base + off, r1 = r0 + (1 << SH);
            const float v0r = re[r0], v0i = im[r0];
            const float v1r = re[r1], v1i = im[r1];
            re[r0] = c * v0r - s * v1r;  im[r0] = c * v0i - s * v1i;
            re[r1] = s * v0r + c * v1r;  im[r1] = s * v0i + c * v1i;
        }
    }
}

// ---------------------------------------------------------------------------
// Tiny pre-kernel: gate coefficients (uniform across all 4096 states) -> d_ws.
// cf[4j..4j+3] = fused RY(ry0)*RX(rx0) for wire j; cf[40+2j..] = (c,s) of RY(ry1).
__global__ void qsa_coef(const float* __restrict__ rx0,
                         const float* __restrict__ ry0,
                         const float* __restrict__ ry1,
                         float* __restrict__ cf) {
    const int j = threadIdx.x;
    if (j < NW) {
        float sx, cx, sy0, cy0, sy1, cy1;
        sincosf(0.5f * rx0[j], &sx,  &cx);
        sincosf(0.5f * ry0[j], &sy0, &cy0);
        sincosf(0.5f * ry1[j], &sy1, &cy1);
        cf[4 * j + 0] =  cy0 * cx;   // ar
        cf[4 * j + 1] =  sy0 * sx;   // ai
        cf[4 * j + 2] = -sy0 * cx;   // br
        cf[4 * j + 3] = -cy0 * sx;   // bi
        cf[40 + 2 * j]     = cy1;
        cf[40 + 2 * j + 1] = sy1;
    }
}

// ---------------------------------------------------------------------------
// Main: one wave (64 threads) per state; 16 amps/thread in registers.
// Layouts: L0 owns bits 0-3, L1 owns bits 4-7, L2 owns bits {8,9,1,0}-ish:
//   L0: i = t<<4 | r
//   L1: i = (t>>4)<<8 | r<<4 | (t&15)
//   L2: i = (r>>2)<<8 | t<<2 | (r&3)
__global__ __launch_bounds__(64) void qsa_main(
    const float* __restrict__ x,
    const float* __restrict__ cf,
    float* __restrict__ out) {

    __shared__ __align__(16) float2 sp[1160];

    const int t = threadIdx.x;
    const int n = blockIdx.x;

    // Uniform coefficient loads (scalar path -> SGPRs)
    float g1[40], g2[20];
    #pragma unroll
    for (int k = 0; k < 40; ++k) g1[k] = cf[k];
    #pragma unroll
    for (int k = 0; k < 20; ++k) g2[k] = cf[40 + k];

    // ---- load row (L0 layout), sum of squares ----
    float re[16], im[16];
    const float* xr = x + ((size_t)n << 10) + (t << 4);
    float ss = 0.f;
    #pragma unroll
    for (int r = 0; r < 16; r += 4) {
        const float4 v = *reinterpret_cast<const float4*>(xr + r);
        re[r] = v.x; re[r + 1] = v.y; re[r + 2] = v.z; re[r + 3] = v.w;
        ss += v.x * v.x + v.y * v.y + v.z * v.z + v.w * v.w;
    }
    #pragma unroll
    for (int off = 32; off > 0; off >>= 1) ss += __shfl_xor(ss, off, 64);
    const float scale = 1.0f / fmaxf(sqrtf(ss), 1e-12f);

    // ================= layer 1 =================
    // Phase A (L0 local bits 0-3 -> wires 9,8,7,6)
    {   // wire 9 (sh=0): input is real, fold in normalization
        const float ar = g1[36], ai = g1[37], br = g1[38], bi = g1[39];
        #pragma unroll
        for (int r = 0; r < 16; r += 2) {
            const float v0 = re[r] * scale, v1 = re[r + 1] * scale;
            re[r]     =  ar * v0 + br * v1;  im[r]     = ai * v0 + bi * v1;
            re[r + 1] = -br * v0 + ar * v1;  im[r + 1] = bi * v0 - ai * v1;
        }
    }
    cgates<1>(re, im, g1[32], g1[33], g1[34], g1[35]);   // wire 8
    cgates<2>(re, im, g1[28], g1[29], g1[30], g1[31]);   // wire 7
    cgates<3>(re, im, g1[24], g1[25], g1[26], g1[27]);   // wire 6

    // T1: write L0 (vector), read L1 (scalar b64)
    #pragma unroll
    for (int r = 0; r < 16; r += 2) {
        const int i = (t << 4) | r;
        *reinterpret_cast<float4*>(&sp[P2i(i)]) =
            make_float4(re[r], im[r], re[r + 1], im[r + 1]);
    }
    __syncthreads();
    {
        const int hi = (t >> 4) << 8, lo = t & 15;
        #pragma unroll
        for (int r = 0; r < 16; ++r) {
            const float2 v = sp[P2i(hi | (r << 4) | lo)];
            re[r] = v.x; im[r] = v.y;
        }
    }

    // Phase B (L1 local bits 4-7 -> wires 5,4,3,2)
    cgates<0>(re, im, g1[20], g1[21], g1[22], g1[23]);   // wire 5
    cgates<1>(re, im, g1[16], g1[17], g1[18], g1[19]);   // wire 4
    cgates<2>(re, im, g1[12], g1[13], g1[14], g1[15]);   // wire 3
    cgates<3>(re, im, g1[ 8], g1[ 9], g1[10], g1[11]);   // wire 2

    // T2: write L1 (scalar), read L2 (vector)
    __syncthreads();
    {
        const int hi = (t >> 4) << 8, lo = t & 15;
        #pragma unroll
        for (int r = 0; r < 16; ++r)
            sp[P2i(hi | (r << 4) | lo)] = make_float2(re[r], im[r]);
    }
    __syncthreads();
    #pragma unroll
    for (int r = 0; r < 16; r += 2) {
        const int i = (((r >> 2) & 3) << 8) | (t << 2) | (r & 3);
        const float4 v = *reinterpret_cast<const float4*>(&sp[P2i(i)]);
        re[r] = v.x; im[r] = v.y; re[r + 1] = v.z; im[r + 1] = v.w;
    }

    // Phase C (L2: r bit2 -> i bit8 -> wire 1; r bit3 -> i bit9 -> wire 0)
    cgates<2>(re, im, g1[4], g1[5], g1[6], g1[7]);       // wire 1
    cgates<3>(re, im, g1[0], g1[1], g1[2], g1[3]);       // wire 0

    // T3: write L2 (vector), read with fused CNOT-ring gather into L0
    __syncthreads();
    #pragma unroll
    for (int r = 0; r < 16; r += 2) {
        const int i = (((r >> 2) & 3) << 8) | (t << 2) | (r & 3);
        *reinterpret_cast<float4*>(&sp[P2i(i)]) =
            make_float4(re[r], im[r], re[r + 1], im[r + 1]);
    }
    __syncthreads();
    {
        const int gt = gperm(t << 4);
        #pragma unroll
        for (int r = 0; r < 16; ++r) {
            const float2 v = sp[P2i(gt ^ gperm(r))];   // gperm(r) folds
            re[r] = v.x; im[r] = v.y;
        }
    }

    // ================= layer 2 (RY only) =================
    // Phase A2 (L0 -> wires 9,8,7,6)
    rgates<0>(re, im, g2[18], g2[19]);   // wire 9
    rgates<1>(re, im, g2[16], g2[17]);   // wire 8
    rgates<2>(re, im, g2[14], g2[15]);   // wire 7
    rgates<3>(re, im, g2[12], g2[13]);   // wire 6

    // T4: write L0 (vector), read L1 (scalar)
    __syncthreads();
    #pragma unroll
    for (int r = 0; r < 16; r += 2) {
        const int i = (t << 4) | r;
        *reinterpret_cast<float4*>(&sp[P2i(i)]) =
            make_float4(re[r], im[r], re[r + 1], im[r + 1]);
    }
    __syncthreads();
    {
        const int hi = (t >> 4) << 8, lo = t & 15;
        #pragma unroll
        for (int r = 0; r < 16; ++r) {
            const float2 v = sp[P2i(hi | (r << 4) | lo)];
            re[r] = v.x; im[r] = v.y;
        }
    }

    // Phase B2 (L1 -> wires 5,4,3,2)
    rgates<0>(re, im, g2[10], g2[11]);   // wire 5
    rgates<1>(re, im, g2[ 8], g2[ 9]);   // wire 4
    rgates<2>(re, im, g2[ 6], g2[ 7]);   // wire 3
    rgates<3>(re, im, g2[ 4], g2[ 5]);   // wire 2

    // T5: write L1 (scalar), read L2 (vector)
    __syncthreads();
    {
        const int hi = (t >> 4) << 8, lo = t & 15;
        #pragma unroll
        for (int r = 0; r < 16; ++r)
            sp[P2i(hi | (r << 4) | lo)] = make_float2(re[r], im[r]);
    }
    __syncthreads();
    #pragma unroll
    for (int r = 0; r < 16; r += 2) {
        const int i = (((r >> 2) & 3) << 8) | (t << 2) | (r & 3);
        const float4 v = *reinterpret_cast<const float4*>(&sp[P2i(i)]);
        re[r] = v.x; im[r] = v.y; re[r + 1] = v.z; im[r + 1] = v.w;
    }

    // Phase C2 (L2 -> wires 1,0)
    rgates<2>(re, im, g2[2], g2[3]);     // wire 1
    rgates<3>(re, im, g2[0], g2[1]);     // wire 0

    // ---- Z expectations in L2 layout ----
    // i = (r>>2)<<8 | t<<2 | (r&3); bits 9,8,1,0 compile-time per r; bits 7..2 from t.
    float sj[6];
    #pragma unroll
    for (int j = 2; j < 8; ++j)
        sj[j - 2] = 1.0f - 2.0f * (float)((t >> (7 - j)) & 1);

    float acc[NW];
    #pragma unroll
    for (int j = 0; j < NW; ++j) acc[j] = 0.f;

    #pragma unroll
    for (int r = 0; r < 16; ++r) {
        const float p = re[r] * re[r] + im[r] * im[r];
        if (r & 8) acc[0] -= p; else acc[0] += p;   // bit9 -> wire 0
        if (r & 4) acc[1] -= p; else acc[1] += p;   // bit8 -> wire 1
        if (r & 2) acc[8] -= p; else acc[8] += p;   // bit1 -> wire 8
        if (r & 1) acc[9] -= p; else acc[9] += p;   // bit0 -> wire 9
        #pragma unroll
        for (int j = 2; j < 8; ++j) acc[j] = fmaf(sj[j - 2], p, acc[j]);
    }

    #pragma unroll
    for (int j = 0; j < NW; ++j) {
        #pragma unroll
        for (int off = 32; off > 0; off >>= 1)
            acc[j] += __shfl_xor(acc[j], off, 64);
    }
    if (t == 0) {
        #pragma unroll
        for (int j = 0; j < NW; ++j) out[(size_t)n * NW + j] = acc[j];
    }
}

extern "C" void kernel_launch(void* const* d_in, const int* in_sizes, int n_in,
                              void* d_out, int out_size, void* d_ws, size_t ws_size,
                              hipStream_t stream) {
    const float* x   = (const float*)d_in[0];
    const float* rx0 = (const float*)d_in[1];
    const float* ry0 = (const float*)d_in[2];
    const float* ry1 = (const float*)d_in[3];
    float* out = (float*)d_out;
    float* cf  = (float*)d_ws;            // 60 floats of gate coefficients
    const int nstates = in_sizes[0] / QDIM;   // 4096

    qsa_coef<<<1, 64, 0, stream>>>(rx0, ry0, ry1, cf);
    qsa_main<<<nstates, 64, 0, stream>>>(x, cf, out);
}